// Round 4
// baseline (398.349 us; speedup 1.0000x reference)
//
#include <hip/hip_runtime.h>

#define MDIM 256
#define BATCH 256
#define DIMINISH 0.5f
#define RPB 8                       // rows per block (slab)
#define SLABS (MDIM / RPB)          // 32 slabs per batch
#define NBLK (BATCH * SLABS)        // 8192 blocks
#define NTHR 256

// One 256-thread block per (batch, 8-row slab). Each wave owns a row PAIR and
// issues all 8 vector loads (2x int4 + 2x float4 per row = 128B/lane) before
// any compute -> high memory-level parallelism. Slabs with r0 >= dl exit
// after one scalar read. Final reduction fused via last-block-done with
// device-scope atomics (cross-XCD safe); counter is reset by hipMemsetAsync
// each launch (graph-capturable), so every replay is identical.
__global__ __launch_bounds__(NTHR) void fused_loss_kernel(
    const int*   __restrict__ y_true,
    const float* __restrict__ y_pred,
    const int*   __restrict__ doc_len,
    float*       __restrict__ partial,
    int*         __restrict__ counter,
    float*       __restrict__ out)
{
    const int blk  = blockIdx.x;
    const int b    = blk >> 5;                    // / SLABS
    const int r0   = (blk & (SLABS - 1)) * RPB;
    const int dl   = doc_len[b];
    const int lane = threadIdx.x & 63;
    const int wid  = threadIdx.x >> 6;

    float sum = 0.0f;
    const int r  = r0 + wid * 2;                  // wave's first row
    const int j0 = lane * 4;                      // first pair index for lane
    if (r < dl && j0 < dl) {
        const size_t e0 = ((size_t)b * (MDIM * MDIM) + (size_t)r * MDIM + (size_t)j0) * 2;
        const size_t e1 = e0 + 2 * MDIM;          // next row (always in-bounds: r+1 <= 255)
        // ---- issue ALL loads first (8 independent 16B loads / lane) ----
        const int4   t0 = *reinterpret_cast<const int4*>(y_true + e0);
        const int4   t1 = *reinterpret_cast<const int4*>(y_true + e0 + 4);
        const int4   u0 = *reinterpret_cast<const int4*>(y_true + e1);
        const int4   u1 = *reinterpret_cast<const int4*>(y_true + e1 + 4);
        const float4 p0 = *reinterpret_cast<const float4*>(y_pred + e0);
        const float4 p1 = *reinterpret_cast<const float4*>(y_pred + e0 + 4);
        const float4 q0 = *reinterpret_cast<const float4*>(y_pred + e1);
        const float4 q1 = *reinterpret_cast<const float4*>(y_pred + e1 + 4);
        // ---- arithmetic masks (no divergent inner branches) ----
        const float m1 = (j0 + 1 < dl) ? 1.0f : 0.0f;
        const float m2 = (j0 + 2 < dl) ? 1.0f : 0.0f;
        const float m3 = (j0 + 3 < dl) ? 1.0f : 0.0f;
        const float rv = (r + 1 < dl) ? 1.0f : 0.0f;   // second row validity
        // pair layout: flags (neg,pos) = (.x,.y)/(.z,.w); preds likewise
        float s0;
        s0  =      ((float)t0.y * __logf(p0.y) + DIMINISH * (float)t0.x * __logf(p0.x));
        s0 += m1 * ((float)t0.w * __logf(p0.w) + DIMINISH * (float)t0.z * __logf(p0.z));
        s0 += m2 * ((float)t1.y * __logf(p1.y) + DIMINISH * (float)t1.x * __logf(p1.x));
        s0 += m3 * ((float)t1.w * __logf(p1.w) + DIMINISH * (float)t1.z * __logf(p1.z));
        float s1;
        s1  =      ((float)u0.y * __logf(q0.y) + DIMINISH * (float)u0.x * __logf(q0.x));
        s1 += m1 * ((float)u0.w * __logf(q0.w) + DIMINISH * (float)u0.z * __logf(q0.z));
        s1 += m2 * ((float)u1.y * __logf(q1.y) + DIMINISH * (float)u1.x * __logf(q1.x));
        s1 += m3 * ((float)u1.w * __logf(q1.w) + DIMINISH * (float)u1.z * __logf(q1.z));
        sum = -(s0 + rv * s1);
    }

    // wave shuffle reduction
    #pragma unroll
    for (int off = 32; off > 0; off >>= 1)
        sum += __shfl_down(sum, off, 64);

    __shared__ float wsum[4];
    __shared__ int   isLast;
    if (lane == 0) wsum[wid] = sum;
    __syncthreads();

    if (threadIdx.x == 0) {
        const float bs = wsum[0] + wsum[1] + wsum[2] + wsum[3];
        __hip_atomic_store(&partial[blk], bs, __ATOMIC_RELEASE, __HIP_MEMORY_SCOPE_AGENT);
        const int old = __hip_atomic_fetch_add(counter, 1, __ATOMIC_ACQ_REL, __HIP_MEMORY_SCOPE_AGENT);
        isLast = (old == NBLK - 1);
    }
    __syncthreads();

    if (isLast) {
        // this block is the last to finish: all partials are globally visible
        const int t = threadIdx.x;
        float s = 0.0f;
        #pragma unroll
        for (int k = 0; k < NBLK / NTHR; ++k)
            s += __hip_atomic_load(&partial[t + k * NTHR], __ATOMIC_RELAXED, __HIP_MEMORY_SCOPE_AGENT);
        float d = (float)doc_len[t];              // NTHR == BATCH == 256

        #pragma unroll
        for (int off = 32; off > 0; off >>= 1) {
            s += __shfl_down(s, off, 64);
            d += __shfl_down(d, off, 64);
        }
        __shared__ float fsum[4], fdl[4];
        if (lane == 0) { fsum[wid] = s; fdl[wid] = d; }
        __syncthreads();
        if (t == 0)
            out[0] = (fsum[0] + fsum[1] + fsum[2] + fsum[3]) /
                     (fdl[0]  + fdl[1]  + fdl[2]  + fdl[3]);
    }
}

extern "C" void kernel_launch(void* const* d_in, const int* in_sizes, int n_in,
                              void* d_out, int out_size, void* d_ws, size_t ws_size,
                              hipStream_t stream)
{
    const int*   y_true  = (const int*)d_in[0];   // (B, M*M, 2) int32
    const float* y_pred  = (const float*)d_in[1]; // (B, M*M, 2) float32
    const int*   doc_len = (const int*)d_in[2];   // (B,) int32
    float*       out     = (float*)d_out;

    int*   counter = (int*)d_ws;                           // 4B at offset 0
    float* partial = (float*)((char*)d_ws + 256);          // 8192 floats

    hipMemsetAsync(counter, 0, sizeof(int), stream);       // capturable memset node
    fused_loss_kernel<<<NBLK, NTHR, 0, stream>>>(y_true, y_pred, doc_len,
                                                 partial, counter, out);
}

// Round 5
// 23.768 us; speedup vs baseline: 16.7599x; 16.7599x over previous
//
#include <hip/hip_runtime.h>

#define MDIM 256
#define BATCH 256
#define DIMINISH 0.5f
#define RPB 8                       // rows per block (slab)
#define SLABS (MDIM / RPB)          // 32 slabs per batch
#define NBLK (BATCH * SLABS)        // 8192 blocks
#define NTHR 256

// Kernel 1: one 256-thread block per (batch, 8-row slab). Each wave owns a
// row PAIR and issues all 8 vector loads (2x int4 + 2x float4 per row =
// 128B/lane) before any compute -> high memory-level parallelism. Slabs with
// r0 >= dl exit after one scalar read. NO device-scope atomics (Round 4
// lesson: agent-scope release atomics cost ~70ns each in cross-XCD cache
// maintenance -> 8192 of them = 600us).
__global__ __launch_bounds__(NTHR) void row_loss_kernel(
    const int*   __restrict__ y_true,
    const float* __restrict__ y_pred,
    const int*   __restrict__ doc_len,
    float*       __restrict__ partial)
{
    const int blk  = blockIdx.x;
    const int b    = blk >> 5;                    // / SLABS
    const int r0   = (blk & (SLABS - 1)) * RPB;
    const int dl   = doc_len[b];
    const int lane = threadIdx.x & 63;
    const int wid  = threadIdx.x >> 6;

    if (r0 >= dl) {                               // whole slab invalid
        if (threadIdx.x == 0) partial[blk] = 0.0f;
        return;
    }

    float sum = 0.0f;
    const int r  = r0 + wid * 2;                  // wave's first row
    const int j0 = lane * 4;                      // first pair index for lane
    if (r < dl && j0 < dl) {
        const size_t e0 = ((size_t)b * (MDIM * MDIM) + (size_t)r * MDIM + (size_t)j0) * 2;
        const size_t e1 = e0 + 2 * MDIM;          // next row (r+1 <= 255, in-bounds)
        // ---- issue ALL loads first (8 independent 16B loads / lane) ----
        const int4   t0 = *reinterpret_cast<const int4*>(y_true + e0);
        const int4   t1 = *reinterpret_cast<const int4*>(y_true + e0 + 4);
        const int4   u0 = *reinterpret_cast<const int4*>(y_true + e1);
        const int4   u1 = *reinterpret_cast<const int4*>(y_true + e1 + 4);
        const float4 p0 = *reinterpret_cast<const float4*>(y_pred + e0);
        const float4 p1 = *reinterpret_cast<const float4*>(y_pred + e0 + 4);
        const float4 q0 = *reinterpret_cast<const float4*>(y_pred + e1);
        const float4 q1 = *reinterpret_cast<const float4*>(y_pred + e1 + 4);
        // ---- arithmetic masks (no divergent inner branches) ----
        const float m1 = (j0 + 1 < dl) ? 1.0f : 0.0f;
        const float m2 = (j0 + 2 < dl) ? 1.0f : 0.0f;
        const float m3 = (j0 + 3 < dl) ? 1.0f : 0.0f;
        const float rv = (r + 1 < dl) ? 1.0f : 0.0f;   // second row validity
        // pair layout: flags (neg,pos) = (.x,.y)/(.z,.w); preds likewise
        float s0;
        s0  =      ((float)t0.y * __logf(p0.y) + DIMINISH * (float)t0.x * __logf(p0.x));
        s0 += m1 * ((float)t0.w * __logf(p0.w) + DIMINISH * (float)t0.z * __logf(p0.z));
        s0 += m2 * ((float)t1.y * __logf(p1.y) + DIMINISH * (float)t1.x * __logf(p1.x));
        s0 += m3 * ((float)t1.w * __logf(p1.w) + DIMINISH * (float)t1.z * __logf(p1.z));
        float s1;
        s1  =      ((float)u0.y * __logf(q0.y) + DIMINISH * (float)u0.x * __logf(q0.x));
        s1 += m1 * ((float)u0.w * __logf(q0.w) + DIMINISH * (float)u0.z * __logf(q0.z));
        s1 += m2 * ((float)u1.y * __logf(q1.y) + DIMINISH * (float)u1.x * __logf(q1.x));
        s1 += m3 * ((float)u1.w * __logf(q1.w) + DIMINISH * (float)u1.z * __logf(q1.z));
        sum = -(s0 + rv * s1);
    }

    // wave shuffle reduction
    #pragma unroll
    for (int off = 32; off > 0; off >>= 1)
        sum += __shfl_down(sum, off, 64);

    __shared__ float wsum[4];
    if (lane == 0) wsum[wid] = sum;
    __syncthreads();
    if (threadIdx.x == 0)
        partial[blk] = wsum[0] + wsum[1] + wsum[2] + wsum[3];
}

// Kernel 2: deterministic reduction of 8192 partials + doc_len sum.
__global__ __launch_bounds__(1024) void final_reduce_kernel(
    const float* __restrict__ partial,
    const int*   __restrict__ doc_len,
    float*       __restrict__ out)
{
    const int t    = threadIdx.x;
    const int lane = t & 63;
    const int wid  = t >> 6;

    float s = 0.0f;
    #pragma unroll
    for (int k = 0; k < NBLK / 1024; ++k)
        s += partial[t + k * 1024];
    float d = (t < BATCH) ? (float)doc_len[t] : 0.0f;

    #pragma unroll
    for (int off = 32; off > 0; off >>= 1) {
        s += __shfl_down(s, off, 64);
        d += __shfl_down(d, off, 64);
    }

    __shared__ float wsum[16], wdl[16];
    if (lane == 0) { wsum[wid] = s; wdl[wid] = d; }
    __syncthreads();

    if (t < 64) {
        float v  = (t < 16) ? wsum[t] : 0.0f;
        float dv = (t < 16) ? wdl[t]  : 0.0f;
        #pragma unroll
        for (int off = 8; off > 0; off >>= 1) {
            v  += __shfl_down(v, off, 64);
            dv += __shfl_down(dv, off, 64);
        }
        if (t == 0) out[0] = v / dv;
    }
}

extern "C" void kernel_launch(void* const* d_in, const int* in_sizes, int n_in,
                              void* d_out, int out_size, void* d_ws, size_t ws_size,
                              hipStream_t stream)
{
    const int*   y_true  = (const int*)d_in[0];   // (B, M*M, 2) int32
    const float* y_pred  = (const float*)d_in[1]; // (B, M*M, 2) float32
    const int*   doc_len = (const int*)d_in[2];   // (B,) int32
    float*       out     = (float*)d_out;
    float*       partial = (float*)d_ws;          // 8192 floats = 32 KB

    row_loss_kernel<<<NBLK, NTHR, 0, stream>>>(y_true, y_pred, doc_len, partial);
    final_reduce_kernel<<<1, 1024, 0, stream>>>(partial, doc_len, out);
}

// Round 6
// 22.673 us; speedup vs baseline: 17.5692x; 1.0483x over previous
//
#include <hip/hip_runtime.h>

#define MDIM 256
#define BATCH 256
#define DIMINISH 0.5f
#define RPB 8                       // rows per block (slab)
#define SLABS (MDIM / RPB)          // 32 slabs per batch
#define NBLK (BATCH * SLABS)        // 8192 blocks
#define NTHR 256

// Kernel 1: one 256-thread block per (batch, 8-row slab), SLAB-MAJOR block
// order (all slab-0 blocks first -> longest-job-first dispatch, dead blocks
// last). Each wave owns a row PAIR; all 8 16B loads are pinned before any
// compute via sched_barrier(0), and __launch_bounds__(256,2) relaxes the
// VGPR target so the loads can actually stay in flight (Round-4/5 kernels
// compiled to 28 VGPRs -> loads were serialized).
__global__ __launch_bounds__(NTHR, 2) void row_loss_kernel(
    const int*   __restrict__ y_true,
    const float* __restrict__ y_pred,
    const int*   __restrict__ doc_len,
    float*       __restrict__ partial)
{
    const int blk  = blockIdx.x;
    const int b    = blk & (BATCH - 1);           // batch varies fastest
    const int r0   = (blk >> 8) * RPB;            // slab-major
    const int dl   = doc_len[b];
    const int lane = threadIdx.x & 63;
    const int wid  = threadIdx.x >> 6;

    if (r0 >= dl) {                               // whole slab invalid
        if (threadIdx.x == 0) partial[blk] = 0.0f;
        return;
    }

    float sum = 0.0f;
    const int r  = r0 + wid * 2;                  // wave's first row
    const int j0 = lane * 4;                      // first pair index for lane
    if (r < dl && j0 < dl) {
        const size_t e0 = ((size_t)b * (MDIM * MDIM) + (size_t)r * MDIM + (size_t)j0) * 2;
        const size_t e1 = e0 + 2 * MDIM;          // next row (r+1 <= 255, in-bounds)
        // ---- issue ALL loads first (8 independent 16B loads / lane) ----
        const int4   t0 = *reinterpret_cast<const int4*>(y_true + e0);
        const int4   t1 = *reinterpret_cast<const int4*>(y_true + e0 + 4);
        const int4   u0 = *reinterpret_cast<const int4*>(y_true + e1);
        const int4   u1 = *reinterpret_cast<const int4*>(y_true + e1 + 4);
        const float4 p0 = *reinterpret_cast<const float4*>(y_pred + e0);
        const float4 p1 = *reinterpret_cast<const float4*>(y_pred + e0 + 4);
        const float4 q0 = *reinterpret_cast<const float4*>(y_pred + e1);
        const float4 q1 = *reinterpret_cast<const float4*>(y_pred + e1 + 4);
        __builtin_amdgcn_sched_barrier(0);        // keep all loads issued first
        // ---- arithmetic masks (no divergent inner branches) ----
        const float m1 = (j0 + 1 < dl) ? 1.0f : 0.0f;
        const float m2 = (j0 + 2 < dl) ? 1.0f : 0.0f;
        const float m3 = (j0 + 3 < dl) ? 1.0f : 0.0f;
        const float rv = (r + 1 < dl) ? 1.0f : 0.0f;   // second row validity
        // pair layout: flags (neg,pos) = (.x,.y)/(.z,.w); preds likewise
        float s0;
        s0  =      ((float)t0.y * __logf(p0.y) + DIMINISH * (float)t0.x * __logf(p0.x));
        s0 += m1 * ((float)t0.w * __logf(p0.w) + DIMINISH * (float)t0.z * __logf(p0.z));
        s0 += m2 * ((float)t1.y * __logf(p1.y) + DIMINISH * (float)t1.x * __logf(p1.x));
        s0 += m3 * ((float)t1.w * __logf(p1.w) + DIMINISH * (float)t1.z * __logf(p1.z));
        float s1;
        s1  =      ((float)u0.y * __logf(q0.y) + DIMINISH * (float)u0.x * __logf(q0.x));
        s1 += m1 * ((float)u0.w * __logf(q0.w) + DIMINISH * (float)u0.z * __logf(q0.z));
        s1 += m2 * ((float)u1.y * __logf(q1.y) + DIMINISH * (float)u1.x * __logf(q1.x));
        s1 += m3 * ((float)u1.w * __logf(q1.w) + DIMINISH * (float)u1.z * __logf(q1.z));
        sum = -(s0 + rv * s1);
    }

    // wave shuffle reduction
    #pragma unroll
    for (int off = 32; off > 0; off >>= 1)
        sum += __shfl_down(sum, off, 64);

    __shared__ float wsum[4];
    if (lane == 0) wsum[wid] = sum;
    __syncthreads();
    if (threadIdx.x == 0)
        partial[blk] = wsum[0] + wsum[1] + wsum[2] + wsum[3];
}

// Kernel 2: deterministic reduction of 8192 partials + doc_len sum.
// 256 threads, 8 independent float4 loads each (all in flight).
__global__ __launch_bounds__(256) void final_reduce_kernel(
    const float* __restrict__ partial,
    const int*   __restrict__ doc_len,
    float*       __restrict__ out)
{
    const int t    = threadIdx.x;
    const int lane = t & 63;
    const int wid  = t >> 6;

    const float4* p4 = reinterpret_cast<const float4*>(partial);  // 2048 float4
    float4 v[8];
    #pragma unroll
    for (int k = 0; k < 8; ++k)
        v[k] = p4[t + k * 256];
    float d = (float)doc_len[t];                 // NTHR == BATCH == 256

    float s = 0.0f;
    #pragma unroll
    for (int k = 0; k < 8; ++k)
        s += (v[k].x + v[k].y) + (v[k].z + v[k].w);

    #pragma unroll
    for (int off = 32; off > 0; off >>= 1) {
        s += __shfl_down(s, off, 64);
        d += __shfl_down(d, off, 64);
    }

    __shared__ float wsum[4], wdl[4];
    if (lane == 0) { wsum[wid] = s; wdl[wid] = d; }
    __syncthreads();
    if (t == 0)
        out[0] = (wsum[0] + wsum[1] + wsum[2] + wsum[3]) /
                 (wdl[0]  + wdl[1]  + wdl[2]  + wdl[3]);
}

extern "C" void kernel_launch(void* const* d_in, const int* in_sizes, int n_in,
                              void* d_out, int out_size, void* d_ws, size_t ws_size,
                              hipStream_t stream)
{
    const int*   y_true  = (const int*)d_in[0];   // (B, M*M, 2) int32
    const float* y_pred  = (const float*)d_in[1]; // (B, M*M, 2) float32
    const int*   doc_len = (const int*)d_in[2];   // (B,) int32
    float*       out     = (float*)d_out;
    float*       partial = (float*)d_ws;          // 8192 floats = 32 KB

    row_loss_kernel<<<NBLK, NTHR, 0, stream>>>(y_true, y_pred, doc_len, partial);
    final_reduce_kernel<<<1, 256, 0, stream>>>(partial, doc_len, out);
}